// Round 1
// baseline (1565.706 us; speedup 1.0000x reference)
//
#include <hip/hip_runtime.h>
#include <cstdint>
#include <cmath>

#define S_LEN 4096
#define H_DIM 2304
#define NQH   8
#define NKVH  4
#define HDIM  256
#define INTER 9216
#define QKV_N 4096   // (NQ + 2*NKV) * HD
#define QH    2048   // NQ*HD
#define KVH   1024   // NKV*HD

typedef __attribute__((ext_vector_type(4))) float  f32x4;
typedef __attribute__((ext_vector_type(8))) __bf16 bf16x8;

__device__ __forceinline__ __bf16 f2bf(float f) {
  union { float f; unsigned u; } x; x.f = f;
  unsigned r = (x.u + 0x7fffu + ((x.u >> 16) & 1u)) >> 16;   // RNE
  union { unsigned short s; __bf16 b; } y; y.s = (unsigned short)r;
  return y.b;
}

// async global->LDS, 16B per lane. LDS dest must be wave-uniform base + lane*16.
__device__ __forceinline__ void g2l16(const void* g, void* l) {
  __builtin_amdgcn_global_load_lds(
      (__attribute__((address_space(1))) void*)(uintptr_t)g,
      (__attribute__((address_space(3))) void*)(uint32_t)(uintptr_t)l, 16, 0, 0);
}

__device__ __forceinline__ float block_sum(float v, float* sbuf) {
  #pragma unroll
  for (int o = 32; o > 0; o >>= 1) v += __shfl_xor(v, o);
  __syncthreads();
  if ((threadIdx.x & 63) == 0) sbuf[threadIdx.x >> 6] = v;
  __syncthreads();
  return sbuf[0] + sbuf[1] + sbuf[2] + sbuf[3];
}

// ---------------- weight conversion: fp32 [K][N] -> bf16 [N][K] (B^T) ---------
__global__ void conv_t_kernel(const float* __restrict__ src, __bf16* __restrict__ dst,
                              int srcStride, int dstStride) {
  __shared__ float t[32][33];
  int tx = threadIdx.x & 31, ty = threadIdx.x >> 5;
  int n0 = blockIdx.x * 32, k0 = blockIdx.y * 32;
  #pragma unroll
  for (int l = 0; l < 4; ++l) {
    int ky = ty + l * 8;
    t[tx][ky] = src[(long)(k0 + ky) * srcStride + n0 + tx];
  }
  __syncthreads();
  #pragma unroll
  for (int l = 0; l < 4; ++l) {
    int ny = ty + l * 8;
    dst[(long)(n0 + ny) * dstStride + k0 + tx] = f2bf(t[ny][tx]);
  }
}

// gate/up interleave permutation: dst row n holds W[:, src_col(n)] so that inside
// each 128-col GEMM tile, frag pairs (j=0,1) and (j=2,3) are (gate, up) at the
// same activation column a = (n>>7)*64 + ((n>>6)&1)*32 + (((n>>4)&3)>>1)*16 + (n&15).
__device__ __forceinline__ int gu_map(int n) {
  int t = n >> 7, w = (n >> 6) & 1, j = (n >> 4) & 3, c = n & 15;
  int a = t * 64 + w * 32 + ((j >> 1) << 4) + c;
  return (j & 1) ? (INTER + a) : a;
}

__global__ void conv_gu_kernel(const float* __restrict__ src, __bf16* __restrict__ dst) {
  __shared__ float t[32][33];
  int tx = threadIdx.x & 31, ty = threadIdx.x >> 5;
  int n0 = blockIdx.x * 32, k0 = blockIdx.y * 32;
  int sc = gu_map(n0 + tx);
  #pragma unroll
  for (int l = 0; l < 4; ++l) {
    int ky = ty + l * 8;
    t[tx][ky] = src[(long)(k0 + ky) * (2 * INTER) + sc];
  }
  __syncthreads();
  #pragma unroll
  for (int l = 0; l < 4; ++l) {
    int ny = ty + l * 8;
    dst[(long)(n0 + ny) * H_DIM + k0 + tx] = f2bf(t[ny][tx]);
  }
}

// ---------------- rmsnorm kernels (H = 2304 = 9*256) --------------------------
__global__ void rms_in_kernel(const float* __restrict__ x, const float* __restrict__ w,
                              __bf16* __restrict__ out) {
  __shared__ float sbuf[4];
  int row = blockIdx.x, tid = threadIdx.x;
  const float* xr = x + (long)row * H_DIM;
  float v[9]; float ss = 0.f;
  #pragma unroll
  for (int i = 0; i < 9; ++i) { v[i] = xr[tid + i * 256]; ss += v[i] * v[i]; }
  ss = block_sum(ss, sbuf);
  float inv = rsqrtf(ss * (1.0f / H_DIM) + 1e-6f);
  #pragma unroll
  for (int i = 0; i < 9; ++i)
    out[(long)row * H_DIM + tid + i * 256] = f2bf(v[i] * inv * (1.f + w[tid + i * 256]));
}

// h = rmsnorm(P)*(1+w_post); resid = h + hidden (written fp32 to d_out);
// x2 = bf16(rmsnorm(resid)*(1+w_pre))
__global__ void rms_post_attn_kernel(const float* __restrict__ P, const float* __restrict__ hidden,
                                     const float* __restrict__ w_post, const float* __restrict__ w_pre,
                                     float* __restrict__ resid, __bf16* __restrict__ x2) {
  __shared__ float sbuf[4];
  int row = blockIdx.x, tid = threadIdx.x;
  const float* pr = P + (long)row * H_DIM;
  const float* hr = hidden + (long)row * H_DIM;
  float pv[9]; float ss = 0.f;
  #pragma unroll
  for (int i = 0; i < 9; ++i) { pv[i] = pr[tid + i * 256]; ss += pv[i] * pv[i]; }
  ss = block_sum(ss, sbuf);
  float inv = rsqrtf(ss * (1.0f / H_DIM) + 1e-6f);
  float rv[9]; float ss2 = 0.f;
  #pragma unroll
  for (int i = 0; i < 9; ++i) {
    int c = tid + i * 256;
    float hn = pv[i] * inv * (1.f + w_post[c]);
    rv[i] = hn + hr[c];
    resid[(long)row * H_DIM + c] = rv[i];
    ss2 += rv[i] * rv[i];
  }
  ss2 = block_sum(ss2, sbuf);
  float inv2 = rsqrtf(ss2 * (1.0f / H_DIM) + 1e-6f);
  #pragma unroll
  for (int i = 0; i < 9; ++i) {
    int c = tid + i * 256;
    x2[(long)row * H_DIM + c] = f2bf(rv[i] * inv2 * (1.f + w_pre[c]));
  }
}

__global__ void rms_final_kernel(const float* __restrict__ x, const float* __restrict__ w,
                                 float* __restrict__ out) {
  __shared__ float sbuf[4];
  int row = blockIdx.x, tid = threadIdx.x;
  const float* xr = x + (long)row * H_DIM;
  float v[9]; float ss = 0.f;
  #pragma unroll
  for (int i = 0; i < 9; ++i) { v[i] = xr[tid + i * 256]; ss += v[i] * v[i]; }
  ss = block_sum(ss, sbuf);
  float inv = rsqrtf(ss * (1.0f / H_DIM) + 1e-6f);
  #pragma unroll
  for (int i = 0; i < 9; ++i)
    out[(long)row * H_DIM + tid + i * 256] = v[i] * inv * (1.f + w[tid + i * 256]);
}

// ---------------- RoPE: qkv fp32 -> Qr/Kr bf16 --------------------------------
__global__ void rope_kernel(const float* __restrict__ qkv, const int* __restrict__ positions,
                            __bf16* __restrict__ Qr, __bf16* __restrict__ Kr) {
  int row = blockIdx.x, tid = threadIdx.x;
  float pos = (float)positions[row];
  const float* src = qkv + (long)row * QKV_N;
  const float LOG_TH_128 = 9.210340371976184f / 128.f;  // ln(10000)/128
  #pragma unroll
  for (int l = 0; l < 4; ++l) {            // 1024 q pairs
    int p = tid + l * 256;
    int hh = p >> 7, d = p & 127;
    float fr = pos * expf(-(float)d * LOG_TH_128);
    float sn, cs; sincosf(fr, &sn, &cs);
    float x1 = src[hh * 256 + d], x2 = src[hh * 256 + d + 128];
    Qr[(long)row * QH + hh * 256 + d]       = f2bf(x1 * cs - x2 * sn);
    Qr[(long)row * QH + hh * 256 + d + 128] = f2bf(x2 * cs + x1 * sn);
  }
  #pragma unroll
  for (int l = 0; l < 2; ++l) {            // 512 k pairs
    int p = tid + l * 256;
    int hh = p >> 7, d = p & 127;
    float fr = pos * expf(-(float)d * LOG_TH_128);
    float sn, cs; sincosf(fr, &sn, &cs);
    float x1 = src[QH + hh * 256 + d], x2 = src[QH + hh * 256 + d + 128];
    Kr[(long)row * KVH + hh * 256 + d]       = f2bf(x1 * cs - x2 * sn);
    Kr[(long)row * KVH + hh * 256 + d + 128] = f2bf(x2 * cs + x1 * sn);
  }
}

// ---------------- GEMM: C[M][N] = A[M][K](bf16) x B[N][K](bf16) ---------------
// m97 structure: 128x128 tile, 4 waves 2x2, BK=32, global_load_lds width 16,
// XOR chunk swizzle on LDS (source-permuted, dest stays lane-contiguous).
// EPI 0: fp32 C.  EPI 1: paired gate/up -> gelu(gate)*up -> bf16 at [M][N/2].
template <int EPI>
__global__ void gemm_bt(const __bf16* __restrict__ A, const __bf16* __restrict__ B,
                        void* __restrict__ Cout, int K, int ldc) {
  __shared__ __bf16 As[128 * 32];
  __shared__ __bf16 Bs[128 * 32];
  int tid = threadIdx.x;
  int wave = tid >> 6, lane = tid & 63;
  int wm = wave >> 1, wn = wave & 1;
  int q4 = lane >> 4, l15 = lane & 15;
  long bm = (long)blockIdx.y * 128, bn = (long)blockIdx.x * 128;

  int srow = tid >> 2;
  int g = (tid & 3) ^ ((srow >> 1) & 3);           // swizzled source chunk
  const __bf16* Ag = A + (bm + srow) * K + g * 8;
  const __bf16* Bg = B + (bn + srow) * K + g * 8;
  __bf16* Asd = As + tid * 8;
  __bf16* Bsd = Bs + tid * 8;

  int aoff[4], boff[4];
  #pragma unroll
  for (int i = 0; i < 4; ++i) {
    int m = wm * 64 + i * 16 + l15;
    aoff[i] = m * 32 + ((q4 ^ ((m >> 1) & 3)) * 8);
    int n = wn * 64 + i * 16 + l15;
    boff[i] = n * 32 + ((q4 ^ ((n >> 1) & 3)) * 8);
  }

  f32x4 acc[4][4] = {};

  for (int k0 = 0; k0 < K; k0 += 32) {
    g2l16(Ag, Asd);
    g2l16(Ag + 64 * (long)K, Asd + 64 * 32);
    g2l16(Bg, Bsd);
    g2l16(Bg + 64 * (long)K, Bsd + 64 * 32);
    Ag += 32; Bg += 32;
    __syncthreads();
    bf16x8 af[4], bfv[4];
    #pragma unroll
    for (int i = 0; i < 4; ++i) af[i]  = *(const bf16x8*)(As + aoff[i]);
    #pragma unroll
    for (int j = 0; j < 4; ++j) bfv[j] = *(const bf16x8*)(Bs + boff[j]);
    #pragma unroll
    for (int i = 0; i < 4; ++i)
      #pragma unroll
      for (int j = 0; j < 4; ++j)
        acc[i][j] = __builtin_amdgcn_mfma_f32_16x16x32_bf16(af[i], bfv[j], acc[i][j], 0, 0, 0);
    __syncthreads();
  }

  if (EPI == 0) {
    float* C = (float*)Cout;
    #pragma unroll
    for (int i = 0; i < 4; ++i)
      #pragma unroll
      for (int r = 0; r < 4; ++r) {
        long m = bm + wm * 64 + i * 16 + q4 * 4 + r;
        #pragma unroll
        for (int j = 0; j < 4; ++j)
          C[m * ldc + bn + wn * 64 + j * 16 + l15] = acc[i][j][r];
      }
  } else {
    __bf16* C = (__bf16*)Cout;
    #pragma unroll
    for (int i = 0; i < 4; ++i)
      #pragma unroll
      for (int r = 0; r < 4; ++r) {
        long m = bm + wm * 64 + i * 16 + q4 * 4 + r;
        #pragma unroll
        for (int jj = 0; jj < 2; ++jj) {
          float gt = acc[i][2 * jj][r];
          float up = acc[i][2 * jj + 1][r];
          float gl = 0.5f * gt * (1.f + tanhf(0.7978845608f * (gt + 0.044715f * gt * gt * gt)));
          long a = (bn >> 1) + wn * 32 + jj * 16 + l15;
          C[m * ldc + a] = f2bf(gl * up);
        }
      }
  }
}

// ---------------- flash attention, sliding window 1024, softcap 50 ------------
// grid (S/64, 8 heads), 256 threads = 4 waves, each wave 16 q-rows.
__global__ void attn_kernel(const __bf16* __restrict__ Qr, const __bf16* __restrict__ Kr,
                            const __bf16* __restrict__ VT, __bf16* __restrict__ AT) {
  __shared__ __bf16 Kt[32 * 256];   // [key][d], chunk-swizzled
  __shared__ __bf16 Vt[256 * 32];   // [d][key], chunk-swizzled
  __shared__ __bf16 Pt[4][16 * 32]; // per-wave P relayout scratch
  int tid = threadIdx.x, wave = tid >> 6, lane = tid & 63;
  int q4 = lane >> 4, l15 = lane & 15;
  int h = blockIdx.y, hk = h >> 1;
  int qb = blockIdx.x * 64;
  int wqb = qb + wave * 16;

  bf16x8 qf[8];
  {
    const __bf16* qp = Qr + (long)(wqb + l15) * QH + h * HDIM + q4 * 8;
    #pragma unroll
    for (int ks = 0; ks < 8; ++ks) qf[ks] = *(const bf16x8*)(qp + ks * 32);
  }
  f32x4 Oa[16] = {};
  float mrow[4] = {-1e30f, -1e30f, -1e30f, -1e30f};
  float lrow[4] = {0.f, 0.f, 0.f, 0.f};

  int lo = qb - 1023; if (lo < 0) lo = 0;
  int t0 = lo >> 5, t1 = (qb + 63) >> 5;
  for (int t = t0; t <= t1; ++t) {
    int k0 = t * 32;
    #pragma unroll
    for (int L = 0; L < 4; ++L) {
      int idx = L * 256 + tid;
      int key = idx >> 5, s5 = idx & 31;
      int c = s5 ^ (key & 31);
      g2l16(Kr + (long)(k0 + key) * KVH + hk * HDIM + c * 8, Kt + idx * 8);
      int dd = idx >> 2, s2 = idx & 3;
      int c2 = s2 ^ ((dd >> 1) & 3);
      g2l16(VT + (long)(hk * HDIM + dd) * S_LEN + k0 + c2 * 8, Vt + idx * 8);
    }
    __syncthreads();
    bool active = (k0 <= wqb + 15) && (k0 + 31 >= wqb - 1023);
    if (active) {
      f32x4 Sa[2] = {};
      #pragma unroll
      for (int ks = 0; ks < 8; ++ks)
        #pragma unroll
        for (int j = 0; j < 2; ++j) {
          int key = j * 16 + l15;
          int cc = (ks * 4 + q4) ^ (key & 31);
          bf16x8 kf = *(const bf16x8*)(Kt + key * 256 + cc * 8);
          Sa[j] = __builtin_amdgcn_mfma_f32_16x16x32_bf16(qf[ks], kf, Sa[j], 0, 0, 0);
        }
      float alpha[4];
      #pragma unroll
      for (int r = 0; r < 4; ++r) {
        int qi = wqb + q4 * 4 + r;
        float s0 = 50.f * tanhf(Sa[0][r] * 0.0625f * 0.02f);
        float s1 = 50.f * tanhf(Sa[1][r] * 0.0625f * 0.02f);
        int kj0 = k0 + l15, kj1 = k0 + 16 + l15;
        s0 = ((kj0 <= qi) && (qi - kj0 < 1024)) ? s0 : -INFINITY;
        s1 = ((kj1 <= qi) && (qi - kj1 < 1024)) ? s1 : -INFINITY;
        float mx = fmaxf(s0, s1);
        #pragma unroll
        for (int o = 1; o < 16; o <<= 1) mx = fmaxf(mx, __shfl_xor(mx, o));
        float mnew = fmaxf(mrow[r], mx);
        alpha[r] = expf(mrow[r] - mnew);
        mrow[r] = mnew;
        float p0 = expf(s0 - mnew);
        float p1 = expf(s1 - mnew);
        float rs = p0 + p1;
        #pragma unroll
        for (int o = 1; o < 16; o <<= 1) rs += __shfl_xor(rs, o);
        lrow[r] = lrow[r] * alpha[r] + rs;
        Pt[wave][(q4 * 4 + r) * 32 + l15]      = f2bf(p0);
        Pt[wave][(q4 * 4 + r) * 32 + 16 + l15] = f2bf(p1);
      }
      #pragma unroll
      for (int f = 0; f < 16; ++f)
        #pragma unroll
        for (int r = 0; r < 4; ++r) Oa[f][r] *= alpha[r];
      asm volatile("s_waitcnt lgkmcnt(0)" ::: "memory");
      bf16x8 pf = *(const bf16x8*)(&Pt[wave][l15 * 32 + q4 * 8]);
      #pragma unroll
      for (int f = 0; f < 16; ++f) {
        int d = f * 16 + l15;
        int cc = q4 ^ ((d >> 1) & 3);
        bf16x8 vf = *(const bf16x8*)(Vt + d * 32 + cc * 8);
        Oa[f] = __builtin_amdgcn_mfma_f32_16x16x32_bf16(pf, vf, Oa[f], 0, 0, 0);
      }
    }
    __syncthreads();
  }
  #pragma unroll
  for (int f = 0; f < 16; ++f)
    #pragma unroll
    for (int r = 0; r < 4; ++r) {
      long qi = wqb + q4 * 4 + r;
      AT[qi * QH + h * HDIM + f * 16 + l15] = f2bf(Oa[f][r] / lrow[r]);
    }
}

// ---------------- launch ------------------------------------------------------
extern "C" void kernel_launch(void* const* d_in, const int* in_sizes, int n_in,
                              void* d_out, int out_size, void* d_ws, size_t ws_size,
                              hipStream_t stream) {
  (void)in_sizes; (void)n_in; (void)out_size; (void)ws_size;
  const int*   positions = (const int*)d_in[0];
  const float* hidden    = (const float*)d_in[1];
  const float* w_qkv     = (const float*)d_in[2];
  const float* w_o       = (const float*)d_in[3];
  const float* w_gu      = (const float*)d_in[4];
  const float* w_dn      = (const float*)d_in[5];
  const float* w_in_ln   = (const float*)d_in[6];
  const float* w_post    = (const float*)d_in[7];
  const float* w_pre     = (const float*)d_in[8];
  const float* w_pff     = (const float*)d_in[9];
  float* out_h   = (float*)d_out;
  float* out_res = out_h + (size_t)S_LEN * H_DIM;

  char* p = (char*)d_ws;
  auto take = [&](size_t b) { char* r = p; p += (b + 255) & ~(size_t)255; return r; };
  __bf16* Wqkv = (__bf16*)take((size_t)QKV_N * H_DIM * 2);      // 18.9 MB
  __bf16* Wo   = (__bf16*)take((size_t)H_DIM * QH * 2);         //  9.4 MB
  __bf16* Wgu  = (__bf16*)take((size_t)2 * INTER * H_DIM * 2);  // 84.9 MB
  __bf16* Wdn  = (__bf16*)take((size_t)H_DIM * INTER * 2);      // 42.5 MB
  __bf16* Xn   = (__bf16*)take((size_t)S_LEN * H_DIM * 2);      // 18.9 MB
  char*   Rbig = take((size_t)S_LEN * INTER * 2);               // 75.5 MB (QKV fp32 / ACT bf16)
  __bf16* Qrb  = (__bf16*)take((size_t)S_LEN * QH * 2);         // 16.8 MB
  __bf16* Krb  = (__bf16*)take((size_t)S_LEN * KVH * 2);        //  8.4 MB
  __bf16* VTb  = (__bf16*)take((size_t)KVH * S_LEN * 2);        //  8.4 MB
  __bf16* ATb  = (__bf16*)take((size_t)S_LEN * QH * 2);         // 16.8 MB
  float*  Pf   = (float*)take((size_t)S_LEN * H_DIM * 4);       // 37.7 MB (P / Mbuf)
  __bf16* X2   = (__bf16*)take((size_t)S_LEN * H_DIM * 2);      // 18.9 MB  (~357 MB total)
  float*  QKV  = (float*)Rbig;
  __bf16* ACT  = (__bf16*)Rbig;
  float*  Mbuf = Pf;

  dim3 blk(256);
  // weight conversions (bf16, transposed to [N][K])
  conv_t_kernel<<<dim3(QKV_N / 32, H_DIM / 32), blk, 0, stream>>>(w_qkv, Wqkv, QKV_N, H_DIM);
  conv_t_kernel<<<dim3(H_DIM / 32, QH / 32),    blk, 0, stream>>>(w_o,   Wo,   H_DIM, QH);
  conv_gu_kernel<<<dim3(2 * INTER / 32, H_DIM / 32), blk, 0, stream>>>(w_gu, Wgu);
  conv_t_kernel<<<dim3(H_DIM / 32, INTER / 32), blk, 0, stream>>>(w_dn,  Wdn,  H_DIM, INTER);
  // layer
  rms_in_kernel<<<S_LEN, blk, 0, stream>>>(hidden, w_in_ln, Xn);
  gemm_bt<0><<<dim3(QKV_N / 128, S_LEN / 128), blk, 0, stream>>>(Xn, Wqkv, QKV, H_DIM, QKV_N);
  rope_kernel<<<S_LEN, blk, 0, stream>>>(QKV, positions, Qrb, Krb);
  conv_t_kernel<<<dim3(KVH / 32, S_LEN / 32), blk, 0, stream>>>(QKV + QH + KVH, VTb, QKV_N, S_LEN);
  attn_kernel<<<dim3(S_LEN / 64, NQH), blk, 0, stream>>>(Qrb, Krb, VTb, ATb);
  gemm_bt<0><<<dim3(H_DIM / 128, S_LEN / 128), blk, 0, stream>>>(ATb, Wo, Pf, QH, H_DIM);
  rms_post_attn_kernel<<<S_LEN, blk, 0, stream>>>(Pf, hidden, w_post, w_pre, out_res, X2);
  gemm_bt<1><<<dim3(2 * INTER / 128, S_LEN / 128), blk, 0, stream>>>(X2, Wgu, ACT, H_DIM, INTER);
  gemm_bt<0><<<dim3(H_DIM / 128, S_LEN / 128), blk, 0, stream>>>(ACT, Wdn, Mbuf, INTER, H_DIM);
  rms_final_kernel<<<S_LEN, blk, 0, stream>>>(Mbuf, w_pff, out_h);
}

// Round 3
// 1263.502 us; speedup vs baseline: 1.2392x; 1.2392x over previous
//
#include <hip/hip_runtime.h>
#include <cstdint>
#include <cmath>

#define S_LEN 4096
#define H_DIM 2304
#define NQH   8
#define NKVH  4
#define HDIM  256
#define INTER 9216
#define QKV_N 4096   // (NQ + 2*NKV) * HD
#define QH    2048   // NQ*HD
#define KVH   1024   // NKV*HD

typedef __attribute__((ext_vector_type(4))) float  f32x4;
typedef __attribute__((ext_vector_type(8))) __bf16 bf16x8;

__device__ __forceinline__ __bf16 f2bf(float f) {
  union { float f; unsigned u; } x; x.f = f;
  unsigned r = (x.u + 0x7fffu + ((x.u >> 16) & 1u)) >> 16;   // RNE
  union { unsigned short s; __bf16 b; } y; y.s = (unsigned short)r;
  return y.b;
}

// async global->LDS, 16B per lane. LDS dest must be wave-uniform base + lane*16.
__device__ __forceinline__ void g2l16(const void* g, void* l) {
  __builtin_amdgcn_global_load_lds(
      (__attribute__((address_space(1))) void*)(uintptr_t)g,
      (__attribute__((address_space(3))) void*)(uint32_t)(uintptr_t)l, 16, 0, 0);
}

__device__ __forceinline__ float block_sum(float v, float* sbuf) {
  #pragma unroll
  for (int o = 32; o > 0; o >>= 1) v += __shfl_xor(v, o);
  __syncthreads();
  if ((threadIdx.x & 63) == 0) sbuf[threadIdx.x >> 6] = v;
  __syncthreads();
  return sbuf[0] + sbuf[1] + sbuf[2] + sbuf[3];
}

// ---------------- weight conversion: fp32 [K][N] -> bf16 [N][K] (B^T) ---------
__global__ void conv_t_kernel(const float* __restrict__ src, __bf16* __restrict__ dst,
                              int srcStride, int dstStride) {
  __shared__ float t[32][33];
  int tx = threadIdx.x & 31, ty = threadIdx.x >> 5;
  int n0 = blockIdx.x * 32, k0 = blockIdx.y * 32;
  #pragma unroll
  for (int l = 0; l < 4; ++l) {
    int ky = ty + l * 8;
    t[tx][ky] = src[(long)(k0 + ky) * srcStride + n0 + tx];
  }
  __syncthreads();
  #pragma unroll
  for (int l = 0; l < 4; ++l) {
    int ny = ty + l * 8;
    dst[(long)(n0 + ny) * dstStride + k0 + tx] = f2bf(t[ny][tx]);
  }
}

// gate/up interleave permutation (see gu_map comment in round 0)
__device__ __forceinline__ int gu_map(int n) {
  int t = n >> 7, w = (n >> 6) & 1, j = (n >> 4) & 3, c = n & 15;
  int a = t * 64 + w * 32 + ((j >> 1) << 4) + c;
  return (j & 1) ? (INTER + a) : a;
}

__global__ void conv_gu_kernel(const float* __restrict__ src, __bf16* __restrict__ dst) {
  __shared__ float t[32][33];
  int tx = threadIdx.x & 31, ty = threadIdx.x >> 5;
  int n0 = blockIdx.x * 32, k0 = blockIdx.y * 32;
  int sc = gu_map(n0 + tx);
  #pragma unroll
  for (int l = 0; l < 4; ++l) {
    int ky = ty + l * 8;
    t[tx][ky] = src[(long)(k0 + ky) * (2 * INTER) + sc];
  }
  __syncthreads();
  #pragma unroll
  for (int l = 0; l < 4; ++l) {
    int ny = ty + l * 8;
    dst[(long)(n0 + ny) * H_DIM + k0 + tx] = f2bf(t[ny][tx]);
  }
}

// ---------------- rmsnorm kernels (H = 2304 = 9*256) --------------------------
__global__ void rms_in_kernel(const float* __restrict__ x, const float* __restrict__ w,
                              __bf16* __restrict__ out) {
  __shared__ float sbuf[4];
  int row = blockIdx.x, tid = threadIdx.x;
  const float* xr = x + (long)row * H_DIM;
  float v[9]; float ss = 0.f;
  #pragma unroll
  for (int i = 0; i < 9; ++i) { v[i] = xr[tid + i * 256]; ss += v[i] * v[i]; }
  ss = block_sum(ss, sbuf);
  float inv = rsqrtf(ss * (1.0f / H_DIM) + 1e-6f);
  #pragma unroll
  for (int i = 0; i < 9; ++i)
    out[(long)row * H_DIM + tid + i * 256] = f2bf(v[i] * inv * (1.f + w[tid + i * 256]));
}

__global__ void rms_post_attn_kernel(const float* __restrict__ P, const float* __restrict__ hidden,
                                     const float* __restrict__ w_post, const float* __restrict__ w_pre,
                                     float* __restrict__ resid, __bf16* __restrict__ x2) {
  __shared__ float sbuf[4];
  int row = blockIdx.x, tid = threadIdx.x;
  const float* pr = P + (long)row * H_DIM;
  const float* hr = hidden + (long)row * H_DIM;
  float pv[9]; float ss = 0.f;
  #pragma unroll
  for (int i = 0; i < 9; ++i) { pv[i] = pr[tid + i * 256]; ss += pv[i] * pv[i]; }
  ss = block_sum(ss, sbuf);
  float inv = rsqrtf(ss * (1.0f / H_DIM) + 1e-6f);
  float rv[9]; float ss2 = 0.f;
  #pragma unroll
  for (int i = 0; i < 9; ++i) {
    int c = tid + i * 256;
    float hn = pv[i] * inv * (1.f + w_post[c]);
    rv[i] = hn + hr[c];
    resid[(long)row * H_DIM + c] = rv[i];
    ss2 += rv[i] * rv[i];
  }
  ss2 = block_sum(ss2, sbuf);
  float inv2 = rsqrtf(ss2 * (1.0f / H_DIM) + 1e-6f);
  #pragma unroll
  for (int i = 0; i < 9; ++i) {
    int c = tid + i * 256;
    x2[(long)row * H_DIM + c] = f2bf(rv[i] * inv2 * (1.f + w_pre[c]));
  }
}

__global__ void rms_final_kernel(const float* __restrict__ x, const float* __restrict__ w,
                                 float* __restrict__ out) {
  __shared__ float sbuf[4];
  int row = blockIdx.x, tid = threadIdx.x;
  const float* xr = x + (long)row * H_DIM;
  float v[9]; float ss = 0.f;
  #pragma unroll
  for (int i = 0; i < 9; ++i) { v[i] = xr[tid + i * 256]; ss += v[i] * v[i]; }
  ss = block_sum(ss, sbuf);
  float inv = rsqrtf(ss * (1.0f / H_DIM) + 1e-6f);
  #pragma unroll
  for (int i = 0; i < 9; ++i)
    out[(long)row * H_DIM + tid + i * 256] = v[i] * inv * (1.f + w[tid + i * 256]);
}

// ---------------- RoPE: qkv fp32 -> Qr/Kr bf16 --------------------------------
__global__ void rope_kernel(const float* __restrict__ qkv, const int* __restrict__ positions,
                            __bf16* __restrict__ Qr, __bf16* __restrict__ Kr) {
  int row = blockIdx.x, tid = threadIdx.x;
  float pos = (float)positions[row];
  const float* src = qkv + (long)row * QKV_N;
  const float LOG_TH_128 = 9.210340371976184f / 128.f;  // ln(10000)/128
  #pragma unroll
  for (int l = 0; l < 4; ++l) {            // 1024 q pairs
    int p = tid + l * 256;
    int hh = p >> 7, d = p & 127;
    float fr = pos * expf(-(float)d * LOG_TH_128);
    float sn, cs; sincosf(fr, &sn, &cs);
    float x1 = src[hh * 256 + d], x2 = src[hh * 256 + d + 128];
    Qr[(long)row * QH + hh * 256 + d]       = f2bf(x1 * cs - x2 * sn);
    Qr[(long)row * QH + hh * 256 + d + 128] = f2bf(x2 * cs + x1 * sn);
  }
  #pragma unroll
  for (int l = 0; l < 2; ++l) {            // 512 k pairs
    int p = tid + l * 256;
    int hh = p >> 7, d = p & 127;
    float fr = pos * expf(-(float)d * LOG_TH_128);
    float sn, cs; sincosf(fr, &sn, &cs);
    float x1 = src[QH + hh * 256 + d], x2 = src[QH + hh * 256 + d + 128];
    Kr[(long)row * KVH + hh * 256 + d]       = f2bf(x1 * cs - x2 * sn);
    Kr[(long)row * KVH + hh * 256 + d + 128] = f2bf(x2 * cs + x1 * sn);
  }
}

// ---------------- GEMM: C[M][N] = A[M][K](bf16) x B[N][K](bf16) ---------------
// 128x128 tile, 4 waves 2x2, BK=64 (32 MFMA per barrier pair), global_load_lds
// width 16, XOR chunk swizzle (source-permuted; LDS dest stays lane-contiguous).
// EPI 0: fp32 C.  EPI 1: paired gate/up -> gelu(gate)*up -> bf16 at [M][N/2].
template <int EPI>
__global__ void gemm_bt(const __bf16* __restrict__ A, const __bf16* __restrict__ B,
                        void* __restrict__ Cout, int K, int ldc) {
  __shared__ __bf16 As[128 * 64];
  __shared__ __bf16 Bs[128 * 64];
  int tid = threadIdx.x;
  int wave = tid >> 6, lane = tid & 63;
  int wm = wave >> 1, wn = wave & 1;
  int q4 = lane >> 4, l15 = lane & 15;
  long bm = (long)blockIdx.y * 128, bn = (long)blockIdx.x * 128;

  // staging: thread handles rows r8 + 32*l (l=0..3), chunk slot tid&7,
  // sourced from global chunk (tid&7)^(row&7); row&7 == r8&7 (32l == 0 mod 8).
  int r8 = tid >> 3;                         // 0..31
  int cs = (tid & 7) ^ (r8 & 7);
  const __bf16* Ag = A + (bm + r8) * K + cs * 8;
  const __bf16* Bg = B + (bn + r8) * K + cs * 8;
  __bf16* Asd = As + tid * 8;
  __bf16* Bsd = Bs + tid * 8;

  // fragment read: row m slot for global chunk g is g ^ (m&7); m&7 == l15&7.
  int moff[4], noff[4];
  #pragma unroll
  for (int i = 0; i < 4; ++i) {
    moff[i] = (wm * 64 + i * 16 + l15) * 64;
    noff[i] = (wn * 64 + i * 16 + l15) * 64;
  }
  int c0 = (q4 ^ (l15 & 7)) * 8;             // ks=0 element offset; ks=1: ^32
  f32x4 acc[4][4] = {};

  for (int k0 = 0; k0 < K; k0 += 64) {
    #pragma unroll
    for (int l = 0; l < 4; ++l) {
      g2l16(Ag + (long)(l * 32) * K, Asd + l * 2048);
      g2l16(Bg + (long)(l * 32) * K, Bsd + l * 2048);
    }
    Ag += 64; Bg += 64;
    __syncthreads();
    #pragma unroll
    for (int ks = 0; ks < 2; ++ks) {
      int cc = c0 ^ (ks * 32);
      bf16x8 af[4], bfv[4];
      #pragma unroll
      for (int i = 0; i < 4; ++i) af[i]  = *(const bf16x8*)(As + moff[i] + cc);
      #pragma unroll
      for (int j = 0; j < 4; ++j) bfv[j] = *(const bf16x8*)(Bs + noff[j] + cc);
      #pragma unroll
      for (int i = 0; i < 4; ++i)
        #pragma unroll
        for (int j = 0; j < 4; ++j)
          acc[i][j] = __builtin_amdgcn_mfma_f32_16x16x32_bf16(af[i], bfv[j], acc[i][j], 0, 0, 0);
    }
    __syncthreads();
  }

  if (EPI == 0) {
    float* C = (float*)Cout;
    #pragma unroll
    for (int i = 0; i < 4; ++i)
      #pragma unroll
      for (int r = 0; r < 4; ++r) {
        long m = bm + wm * 64 + i * 16 + q4 * 4 + r;
        #pragma unroll
        for (int j = 0; j < 4; ++j)
          C[m * ldc + bn + wn * 64 + j * 16 + l15] = acc[i][j][r];
      }
  } else {
    __bf16* C = (__bf16*)Cout;
    #pragma unroll
    for (int i = 0; i < 4; ++i)
      #pragma unroll
      for (int r = 0; r < 4; ++r) {
        long m = bm + wm * 64 + i * 16 + q4 * 4 + r;
        #pragma unroll
        for (int jj = 0; jj < 2; ++jj) {
          float gt = acc[i][2 * jj][r];
          float up = acc[i][2 * jj + 1][r];
          float u = 0.7978845608f * (gt + 0.044715f * gt * gt * gt);
          float e = __builtin_amdgcn_exp2f(u * 2.8853900817779268f);
          float gl = gt * (1.0f - __builtin_amdgcn_rcpf(e + 1.0f));
          long a = (bn >> 1) + wn * 32 + jj * 16 + l15;
          C[m * ldc + a] = f2bf(gl * up);
        }
      }
  }
}

// ---------------- flash attention, sliding window 1024, softcap 50 ------------
// Fixed-max softmax: softcap bounds s to (-50,50) so p=exp(s) stays in range.
// No running max, no rescale; l reduced once at the end. 64-key tiles.
__global__ void attn_kernel(const __bf16* __restrict__ Qr, const __bf16* __restrict__ Kr,
                            const __bf16* __restrict__ VT, __bf16* __restrict__ AT) {
  __shared__ __bf16 Kt[64 * 256];   // [key][d], chunk slot = c ^ (key&7)
  __shared__ __bf16 Vt[256 * 64];   // [d][key], chunk slot = c ^ (d&7)
  __shared__ __bf16 Pt[4][16 * 72]; // per-wave P relayout, row stride 72
  int tid = threadIdx.x, wave = tid >> 6, lane = tid & 63;
  int q4 = lane >> 4, l15 = lane & 15;
  int h = blockIdx.y, hk = h >> 1;
  int qb = blockIdx.x * 64;
  int wqb = qb + wave * 16;

  bf16x8 qf[8];
  {
    const __bf16* qp = Qr + (long)(wqb + l15) * QH + h * HDIM + q4 * 8;
    #pragma unroll
    for (int ks = 0; ks < 8; ++ks) qf[ks] = *(const bf16x8*)(qp + ks * 32);
  }
  f32x4 Oa[16] = {};
  float lsum[4] = {0.f, 0.f, 0.f, 0.f};

  // staging bases (k0-independent parts). 8 chunks each for K and V per thread:
  // Kt rows (tid>>5)+8*l (l=0..7), Vt rows (tid>>3)+32*l (l=0..7) — full 2048
  // chunks per buffer. Row parity invariant: rows step by multiples of 8.
  int csk = (tid & 31) ^ ((tid >> 5) & 7);
  const __bf16* Kh = Kr + (long)(tid >> 5) * KVH + hk * HDIM + csk * 8;
  int csv = (tid & 7) ^ ((tid >> 3) & 7);
  const __bf16* Vh = VT + (long)(hk * HDIM + (tid >> 3)) * S_LEN + csv * 8;

  int lo = qb - 1023; if (lo < 0) lo = 0;
  int t0 = lo >> 6, t1 = qb >> 6;
  for (int t = t0; t <= t1; ++t) {
    int k0 = t * 64;
    #pragma unroll
    for (int l = 0; l < 8; ++l) {
      g2l16(Kh + ((long)k0 + l * 8) * KVH, Kt + tid * 8 + l * 2048);
      g2l16(Vh + k0 + (long)(l * 32) * S_LEN, Vt + tid * 8 + l * 2048);
    }
    __syncthreads();
    bool active = (k0 <= wqb + 15) && (k0 + 63 >= wqb - 1023);
    if (active) {
      f32x4 Sa[4] = {};
      #pragma unroll
      for (int ks = 0; ks < 8; ++ks)
        #pragma unroll
        for (int j = 0; j < 4; ++j) {
          int key = j * 16 + l15;
          int cc = (ks * 4 + q4) ^ (l15 & 7);       // key&7 == l15&7
          bf16x8 kf = *(const bf16x8*)(Kt + key * 256 + cc * 8);
          Sa[j] = __builtin_amdgcn_mfma_f32_16x16x32_bf16(qf[ks], kf, Sa[j], 0, 0, 0);
        }
      #pragma unroll
      for (int r = 0; r < 4; ++r) {
        int qi = wqb + q4 * 4 + r;
        #pragma unroll
        for (int j = 0; j < 4; ++j) {
          int kj = k0 + j * 16 + l15;
          // s = 50*tanh(Sa*scale/50); p = exp(s) = exp2(72.1348 - 144.2695/(e+1))
          float y = Sa[j][r] * 1.25e-3f;            // * SCALE(1/16) / 50
          float e = __builtin_amdgcn_exp2f(y * 2.8853900817779268f);
          float p = __builtin_amdgcn_exp2f(72.13475204444817f
                     - 144.26950408889634f * __builtin_amdgcn_rcpf(e + 1.0f));
          bool ok = (kj <= qi) && (qi - kj < 1024);
          p = ok ? p : 0.0f;
          lsum[r] += p;
          Pt[wave][(q4 * 4 + r) * 72 + j * 16 + l15] = f2bf(p);
        }
      }
      asm volatile("s_waitcnt lgkmcnt(0)" ::: "memory");
      bf16x8 pf[2];
      #pragma unroll
      for (int ks = 0; ks < 2; ++ks)
        pf[ks] = *(const bf16x8*)(&Pt[wave][l15 * 72 + ks * 32 + q4 * 8]);
      #pragma unroll
      for (int f = 0; f < 16; ++f) {
        int d = f * 16 + l15;
        #pragma unroll
        for (int ks = 0; ks < 2; ++ks) {
          int cc = (ks * 4 + q4) ^ (l15 & 7);       // d&7 == l15&7
          bf16x8 vf = *(const bf16x8*)(Vt + d * 64 + cc * 8);
          Oa[f] = __builtin_amdgcn_mfma_f32_16x16x32_bf16(pf[ks], vf, Oa[f], 0, 0, 0);
        }
      }
    }
    __syncthreads();
  }
  #pragma unroll
  for (int r = 0; r < 4; ++r) {
    float v = lsum[r];
    #pragma unroll
    for (int o = 1; o < 16; o <<= 1) v += __shfl_xor(v, o);
    lsum[r] = __builtin_amdgcn_rcpf(v);
  }
  #pragma unroll
  for (int f = 0; f < 16; ++f)
    #pragma unroll
    for (int r = 0; r < 4; ++r) {
      long qi = wqb + q4 * 4 + r;
      AT[qi * QH + h * HDIM + f * 16 + l15] = f2bf(Oa[f][r] * lsum[r]);
    }
}

// ---------------- launch ------------------------------------------------------
extern "C" void kernel_launch(void* const* d_in, const int* in_sizes, int n_in,
                              void* d_out, int out_size, void* d_ws, size_t ws_size,
                              hipStream_t stream) {
  (void)in_sizes; (void)n_in; (void)out_size; (void)ws_size;
  const int*   positions = (const int*)d_in[0];
  const float* hidden    = (const float*)d_in[1];
  const float* w_qkv     = (const float*)d_in[2];
  const float* w_o       = (const float*)d_in[3];
  const float* w_gu      = (const float*)d_in[4];
  const float* w_dn      = (const float*)d_in[5];
  const float* w_in_ln   = (const float*)d_in[6];
  const float* w_post    = (const float*)d_in[7];
  const float* w_pre     = (const float*)d_in[8];
  const float* w_pff     = (const float*)d_in[9];
  float* out_h   = (float*)d_out;
  float* out_res = out_h + (size_t)S_LEN * H_DIM;

  char* p = (char*)d_ws;
  auto take = [&](size_t b) { char* r = p; p += (b + 255) & ~(size_t)255; return r; };
  __bf16* Wqkv = (__bf16*)take((size_t)QKV_N * H_DIM * 2);
  __bf16* Wo   = (__bf16*)take((size_t)H_DIM * QH * 2);
  __bf16* Wgu  = (__bf16*)take((size_t)2 * INTER * H_DIM * 2);
  __bf16* Wdn  = (__bf16*)take((size_t)H_DIM * INTER * 2);
  __bf16* Xn   = (__bf16*)take((size_t)S_LEN * H_DIM * 2);
  char*   Rbig = take((size_t)S_LEN * INTER * 2);
  __bf16* Qrb  = (__bf16*)take((size_t)S_LEN * QH * 2);
  __bf16* Krb  = (__bf16*)take((size_t)S_LEN * KVH * 2);
  __bf16* VTb  = (__bf16*)take((size_t)KVH * S_LEN * 2);
  __bf16* ATb  = (__bf16*)take((size_t)S_LEN * QH * 2);
  float*  Pf   = (float*)take((size_t)S_LEN * H_DIM * 4);
  __bf16* X2   = (__bf16*)take((size_t)S_LEN * H_DIM * 2);
  float*  QKV  = (float*)Rbig;
  __bf16* ACT  = (__bf16*)Rbig;
  float*  Mbuf = Pf;

  dim3 blk(256);
  conv_t_kernel<<<dim3(QKV_N / 32, H_DIM / 32), blk, 0, stream>>>(w_qkv, Wqkv, QKV_N, H_DIM);
  conv_t_kernel<<<dim3(H_DIM / 32, QH / 32),    blk, 0, stream>>>(w_o,   Wo,   H_DIM, QH);
  conv_gu_kernel<<<dim3(2 * INTER / 32, H_DIM / 32), blk, 0, stream>>>(w_gu, Wgu);
  conv_t_kernel<<<dim3(H_DIM / 32, INTER / 32), blk, 0, stream>>>(w_dn,  Wdn,  H_DIM, INTER);
  rms_in_kernel<<<S_LEN, blk, 0, stream>>>(hidden, w_in_ln, Xn);
  gemm_bt<0><<<dim3(QKV_N / 128, S_LEN / 128), blk, 0, stream>>>(Xn, Wqkv, QKV, H_DIM, QKV_N);
  rope_kernel<<<S_LEN, blk, 0, stream>>>(QKV, positions, Qrb, Krb);
  conv_t_kernel<<<dim3(KVH / 32, S_LEN / 32), blk, 0, stream>>>(QKV + QH + KVH, VTb, QKV_N, S_LEN);
  attn_kernel<<<dim3(S_LEN / 64, NQH), blk, 0, stream>>>(Qrb, Krb, VTb, ATb);
  gemm_bt<0><<<dim3(H_DIM / 128, S_LEN / 128), blk, 0, stream>>>(ATb, Wo, Pf, QH, H_DIM);
  rms_post_attn_kernel<<<S_LEN, blk, 0, stream>>>(Pf, hidden, w_post, w_pre, out_res, X2);
  gemm_bt<1><<<dim3(2 * INTER / 128, S_LEN / 128), blk, 0, stream>>>(X2, Wgu, ACT, H_DIM, INTER);
  gemm_bt<0><<<dim3(H_DIM / 128, S_LEN / 128), blk, 0, stream>>>(ACT, Wdn, Mbuf, INTER, H_DIM);
  rms_final_kernel<<<S_LEN, blk, 0, stream>>>(Mbuf, w_pff, out_h);
}